// Round 14
// baseline (31184.479 us; speedup 1.0000x reference)
//
#include <hip/hip_runtime.h>
#include <hip/hip_bf16.h>
#include <stdint.h>

// ---------------------------------------------------------------------------
// Persistent-kernel LSTM decoder for MI355X — v14: v13 (fragment-packed,
// elastic rings) + LDS-LANDED recurrent loads (global_load_lds, 32/28 deep
// in flight, zero VGPR cost) + PER-WAVE fine-grained waits (wave w polls only
// its 16 k-slice producers; guard slots unioned across waves before stores).
//   g1@s: wave w: own[w*16+l]>=s+1 (l<16), g2[w*16+l-16]>=max(1,s-4) (16<=l<32)
//   g2@s: wave w: g1[w*16+l]>=s   (l<16), g2[w*16+l-16]>=s+1        (16<=l<32)
// LDS: 128KB landing ring (4 waves x 8 slots x 4KB), epilogue red/fcred
// overlaid (guarded by an extra __syncthreads before red writes).
// ---------------------------------------------------------------------------

#define NSUP 2003

typedef __attribute__((ext_vector_type(8))) short bf16x8;
typedef __attribute__((ext_vector_type(4))) float f32x4;
typedef const __attribute__((address_space(1))) unsigned int* GPTR;
typedef __attribute__((address_space(3))) unsigned int* LPTR;

// ws layout (bytes)
#define OFF_WTXT   0ull
#define OFF_WHH1   8388608ull
#define OFF_WPREV  16777216ull
#define OFF_WIH2   17825792ull
#define OFF_WHH2   26214400ull
#define OFF_FCW    34603008ull
#define OFF_BIAS2  34799616ull
#define OFF_PS_H1R 34816000ull    // pstyle at launch; h1 ring 8 x 262144 after init
#define OFF_ENC    36913152ull    // 400 slices x 262144, fragment-packed
#define OFF_STYLET 141606912ull   // ENC tail scratch; overwritten by k_pack_enc
#define OFF_PREV   141770752ull   // tau x 32768, fragment-packed
#define OFF_H2     208093184ull   // 2 slots x 262144, fragment-packed
#define OFF_EPG1   208617472ull   // g1 epochs: 128 x 4B
#define OFF_EPG2   208621568ull   // g2 epochs: 128 x 4B
#define WS_NEED    208717824ull

__device__ __forceinline__ unsigned short f2bf(float f) {
  __hip_bfloat16 b = __float2bfloat16(f);
  return *reinterpret_cast<unsigned short*>(&b);
}
__device__ __forceinline__ float sigm(float x) { return 1.f / (1.f + __expf(-x)); }
__device__ __forceinline__ float tanh_(float x) {
  x = fminf(15.f, fmaxf(-15.f, x));
  float e = __expf(2.f * x);
  return (e - 1.f) / (e + 1.f);
}
__device__ __forceinline__ int origRow(int rp) {
  return ((rp >> 4) & 3) * 1024 + (rp >> 6) * 16 + (rp & 15);
}

#define VMW(n) asm volatile("s_waitcnt vmcnt(" #n ")" ::: "memory")

__device__ __forceinline__ void ldx4(bf16x8& d, const void* p) {      // plain
  asm volatile("global_load_dwordx4 %0, %1, off" : "=v"(d) : "v"(p));
}

// fragment address of unit n (0..1023), col c (0..127) within a 256KB slice
__device__ __forceinline__ size_t fragOff(int c, int n) {
  return (size_t)(c >> 6) * 131072 + (size_t)(n >> 8) * 32768 +
         (size_t)((n >> 5) & 7) * 4096 + (size_t)((c >> 4) & 3) * 1024 +
         (size_t)((((n >> 3) & 3) * 16) + (c & 15)) * 16 + (size_t)(n & 7) * 2;
}

// ------------------------------- pack kernels -------------------------------
__global__ void k_pack_w1(const float* __restrict__ wih1, const float* __restrict__ whh1,
                          unsigned char* __restrict__ ws) {
  int idx = blockIdx.x * 256 + threadIdx.x;            // 4096*1024
  int rp = idx >> 10, k = idx & 1023;
  int orig = origRow(rp);
  ((unsigned short*)(ws + OFF_WTXT))[idx] = f2bf(wih1[(size_t)orig * 1424 + k]);
  ((unsigned short*)(ws + OFF_WHH1))[idx] = f2bf(whh1[(size_t)orig * 1024 + k]);
}
__global__ void k_pack_w2(const float* __restrict__ wih2, const float* __restrict__ whh2,
                          unsigned char* __restrict__ ws) {
  int idx = blockIdx.x * 256 + threadIdx.x;
  int rp = idx >> 10, k = idx & 1023;
  int orig = origRow(rp);
  ((unsigned short*)(ws + OFF_WIH2))[idx] = f2bf(wih2[(size_t)orig * 1024 + k]);
  ((unsigned short*)(ws + OFF_WHH2))[idx] = f2bf(whh2[(size_t)orig * 1024 + k]);
}
__global__ void k_bias2(const float* __restrict__ bih2, const float* __restrict__ bhh2,
                        unsigned char* __restrict__ ws) {
  int rp = blockIdx.x * 256 + threadIdx.x;
  if (rp >= 4096) return;
  int orig = origRow(rp);
  ((float*)(ws + OFF_BIAS2))[rp] = bih2[orig] + bhh2[orig];
}
__global__ void k_pack_wprev(const float* __restrict__ wih1, unsigned char* __restrict__ ws) {
  int idx = blockIdx.x * 256 + threadIdx.x;            // 4096*128
  int rp = idx >> 7, k = idx & 127;
  int orig = origRow(rp);
  ((unsigned short*)(ws + OFF_WPREV))[idx] =
      (k < 80) ? f2bf(wih1[(size_t)orig * 1424 + 1344 + k]) : (unsigned short)0;
}
__global__ void k_pack_fc(const float* __restrict__ fcw, unsigned char* __restrict__ ws) {
  int idx = blockIdx.x * 256 + threadIdx.x;            // 96*1024
  int r = idx >> 10, k = idx & 1023;
  ((unsigned short*)(ws + OFF_FCW))[idx] =
      (r < 80) ? f2bf(fcw[(size_t)r * 1024 + k]) : (unsigned short)0;
}
__global__ void k_pack_enc(const float* __restrict__ enc, unsigned char* __restrict__ ws) {
  size_t i = (size_t)blockIdx.x * 256 + threadIdx.x;   // 13,107,200 float4's
  float4 v = ((const float4*)enc)[i];
  union { unsigned short u[4]; unsigned long long ll; } z;
  z.u[0] = f2bf(v.x); z.u[1] = f2bf(v.y); z.u[2] = f2bf(v.z); z.u[3] = f2bf(v.w);
  int b  = (int)(i / (400 * 256));
  int tp = (int)((i >> 8) % 400);
  int u4 = (int)(i & 255);
  *(unsigned long long*)(ws + OFF_ENC + (size_t)tp * 262144 + fragOff(b, u4 * 4)) = z.ll;
}
__global__ void k_styleT(const float* __restrict__ style, float* __restrict__ sT) {
  int idx = blockIdx.x * 256 + threadIdx.x;            // 320*128
  int j = idx >> 7, n = idx & 127;
  sT[idx] = style[n * 320 + j];
}
__global__ void k_pstyle(const float* __restrict__ wih1, const float* __restrict__ bih1,
                         const float* __restrict__ bhh1, const float* __restrict__ sT,
                         unsigned char* __restrict__ ws) {
  int n = threadIdx.x & 127, rsub = threadIdx.x >> 7;
  int rp = blockIdx.x * 2 + rsub;
  int orig = origRow(rp);
  const float* wr = wih1 + (size_t)orig * 1424 + 1024;
  float a0 = 0.f, a1 = 0.f, a2 = 0.f, a3 = 0.f;
  for (int j = 0; j < 320; j += 4) {
    a0 += wr[j + 0] * sT[(j + 0) * 128 + n];
    a1 += wr[j + 1] * sT[(j + 1) * 128 + n];
    a2 += wr[j + 2] * sT[(j + 2) * 128 + n];
    a3 += wr[j + 3] * sT[(j + 3) * 128 + n];
  }
  ((float*)(ws + OFF_PS_H1R))[rp * 128 + n] = (a0 + a1) + (a2 + a3) + bih1[orig] + bhh1[orig];
}
__global__ void k_pack_prev(const float* __restrict__ mel, unsigned char* __restrict__ ws) {
  __shared__ unsigned short pl[64][80];
  int b = blockIdx.y, tt0 = blockIdx.x * 64;
  int tid = threadIdx.x;
  int ttl = tid & 63, mi = tid >> 6;
  for (int m = mi; m < 80; m += 4) {
    int tau = tt0 + ttl;
    if (tau <= 1998) pl[ttl][m] = f2bf(mel[((size_t)b * 80 + m) * 2000 + tau]);
  }
  __syncthreads();
  for (int idx = tid; idx < 64 * 80; idx += 256) {
    int t2 = idx / 80, m = idx % 80;
    int tau = tt0 + t2;
    if (tau <= 1998) {
      size_t off = (size_t)(tau + 1) * 32768 + (size_t)(b >> 6) * 16384 +
                   (size_t)(m >> 5) * 4096 + (size_t)((b >> 4) & 3) * 1024 +
                   (size_t)((((m >> 3) & 3) * 16) + (b & 15)) * 16 + (size_t)(m & 7) * 2;
      *(unsigned short*)(ws + OFF_PREV + off) = pl[t2][m];
    }
  }
}

// ------------------------------ persistent kernel ---------------------------
__global__ __launch_bounds__(256, 1) void k_persist(unsigned char* __restrict__ ws,
                                                    float* __restrict__ out,
                                                    const float* __restrict__ fc_b) {
  __shared__ __align__(1024) unsigned char smem[131072];  // landing ring UNION epilogue
  float (*red)[64][68] = (float(*)[64][68])smem;          // 69632 B (after barrier)
  float (*fcred)[16][68] = (float(*)[16][68])(smem + 69632);  // 17408 B

  const int tid = threadIdx.x, bid = blockIdx.x;
  const int w = tid >> 6, l = tid & 63;
  const int r15 = l & 15, khi = l >> 4;
  const bool isG1 = bid < 128;
  const int lb = bid & 127, rb = lb >> 1, cg = lb & 1;
  const bool fcB = (!isG1) && (lb < 12);
  const int u6 = lb >> 1;
  const int ecol = tid & 63, quad = tid >> 6;

  // ---------------- resident A fragments ----------------
  bf16x8 avr[4][16];
  bf16x8 avp[4];
#pragma unroll
  for (int i = 0; i < 4; ++i) {
    const size_t row = (size_t)(rb * 64 + 16 * i + r15);
    const unsigned char* pa =
        ws + (isG1 ? OFF_WTXT : OFF_WIH2) + row * 2048 + w * 512 + khi * 16;
    const unsigned char* ph =
        ws + (isG1 ? OFF_WHH1 : OFF_WHH2) + row * 2048 + w * 512 + khi * 16;
#pragma unroll
    for (int t = 0; t < 8; ++t) avr[i][t] = *(const bf16x8*)(pa + t * 64);
#pragma unroll
    for (int t = 0; t < 8; ++t) avr[i][8 + t] = *(const bf16x8*)(ph + t * 64);
    if (isG1)
      avp[i] = *(const bf16x8*)(ws + OFF_WPREV + row * 256 + w * 64 + khi * 16);
  }
  bf16x8 fcav[8];
  if (fcB) {
    const unsigned char* pf = ws + OFF_FCW + (size_t)(u6 * 16 + r15) * 2048 + w * 512 + khi * 16;
#pragma unroll
    for (int t = 0; t < 8; ++t) fcav[t] = *(const bf16x8*)(pf + t * 64);
  }
  float pstb[4][4];
  if (isG1) {
    const float* PS = (const float*)(ws + OFF_PS_H1R);
#pragma unroll
    for (int g = 0; g < 4; ++g)
#pragma unroll
      for (int u = 0; u < 4; ++u)
        pstb[g][u] = PS[(size_t)(rb * 64 + 16 * g + quad * 4 + u) * 128 + cg * 64 + ecol];
  }

  // producer h-store fragment offset (one 8B store per thread)
  const size_t hfragOff = (size_t)cg * 131072 + (size_t)(rb >> 4) * 32768 +
                          (size_t)((rb >> 1) & 7) * 4096 + (size_t)(ecol >> 4) * 1024 +
                          (size_t)((((rb & 1) * 2 + (quad >> 1)) * 16) + (ecol & 15)) * 16 +
                          (size_t)(quad & 1) * 8;
  // consumer fragment base for this (cg, w): + t*4096 + j*1024 + l*16
  const size_t cfragW = (size_t)cg * 131072 + (size_t)w * 32768;
  unsigned char* landW = smem + w * 32768;   // wave's 8-slot landing ring

  float fcbr[4];
#pragma unroll
  for (int q = 0; q < 4; ++q) {
    int m = u6 * 16 + quad * 4 + q;
    fcbr[q] = (fcB && m < 80) ? fc_b[m] : 0.f;
  }
  float cst[4] = {0.f, 0.f, 0.f, 0.f};
  const f32x4 zero4 = {0.f, 0.f, 0.f, 0.f};

  // epoch slots; publish with RELEASE (agent)
  unsigned* myslot = (unsigned*)(ws + (isG1 ? OFF_EPG1 : OFF_EPG2) +
                                 (size_t)(cg * 64 + rb) * 4);
  auto epPub = [&](unsigned v) __attribute__((always_inline)) {
    __hip_atomic_store(myslot, v, __ATOMIC_RELEASE, __HIP_MEMORY_SCOPE_AGENT);
  };
  // per-wave poll pointers: lanes 0..15 -> arr1[w*16+l]; lanes 16..31 -> arr2[w*16+l-16]
  const unsigned* pw1 = (const unsigned*)(ws + OFF_EPG1 +
                         (size_t)(cg * 64 + w * 16 + (l & 15)) * 4);
  const unsigned* pw2 = (const unsigned*)(ws + OFF_EPG2 +
                         (size_t)(cg * 64 + w * 16 + (l & 15)) * 4);
  // g1 waits: own(EPG1)>=t1, guard(EPG2)>=t2 ; g2 waits: EPG1>=t1, own(EPG2)>=t2
  auto waitWave = [&](unsigned t1, unsigned t2) __attribute__((always_inline)) {
    for (long it = 0; it < 8000000; ++it) {
      unsigned v1 = __hip_atomic_load(pw1, __ATOMIC_RELAXED, __HIP_MEMORY_SCOPE_AGENT);
      unsigned v2 = __hip_atomic_load(pw2, __ATOMIC_RELAXED, __HIP_MEMORY_SCOPE_AGENT);
      bool ok = (l < 16) ? (v1 >= t1) : (l < 32) ? (v2 >= t2) : true;
      if (__all(ok)) break;
      __builtin_amdgcn_s_sleep(1);
    }
  };

  // ---- init publish ----
  __syncthreads();
  if (tid == 0) epPub(1u);

  // ---- one-time global init barrier (pstyle reads before any h1-ring store) ----
  {
    if (w == 0) {
      const unsigned* a0 = (const unsigned*)(ws + OFF_EPG1 + (size_t)l * 4);
      const unsigned* a1 = (const unsigned*)(ws + OFF_EPG1 + (size_t)(64 + l) * 4);
      const unsigned* b0 = (const unsigned*)(ws + OFF_EPG2 + (size_t)l * 4);
      const unsigned* b1 = (const unsigned*)(ws + OFF_EPG2 + (size_t)(64 + l) * 4);
      for (long it = 0; it < 8000000; ++it) {
        unsigned v0 = __hip_atomic_load(a0, __ATOMIC_RELAXED, __HIP_MEMORY_SCOPE_AGENT);
        unsigned v1 = __hip_atomic_load(a1, __ATOMIC_RELAXED, __HIP_MEMORY_SCOPE_AGENT);
        unsigned v2 = __hip_atomic_load(b0, __ATOMIC_RELAXED, __HIP_MEMORY_SCOPE_AGENT);
        unsigned v3 = __hip_atomic_load(b1, __ATOMIC_RELAXED, __HIP_MEMORY_SCOPE_AGENT);
        if (__all((v0 >= 1u) && (v1 >= 1u) && (v2 >= 1u) && (v3 >= 1u))) break;
        __builtin_amdgcn_s_sleep(2);
      }
    }
    __syncthreads();
  }

  bf16x8 bvr[4][4];   // statics register ring (g1 only)

#pragma unroll 1
  for (int s = 0; s < NSUP; ++s) {
    const bool g1a = isG1 && (s <= 1999);
    const bool g2a = (!isG1) && (s >= 2) && (s <= 2001);   // gates2[s-2]
    const bool fca = fcB && (s >= 3) && (s <= 2002);       // frame[s-3]
    const bool g2run = g2a || fca;

    if (g1a) {
      f32x4 acc[4][4];
#pragma unroll
      for (int i = 0; i < 4; ++i)
#pragma unroll
        for (int j = 0; j < 4; ++j) acc[i][j] = zero4;

      // ---- shadow statics: enc + prev (9 t), register ring-4 ----
      const int tp = (s < 399) ? s : 399;
      const unsigned char* encw = ws + OFF_ENC + (size_t)tp * 262144 + cfragW + (size_t)l * 16;
      const unsigned char* prvw = ws + OFF_PREV + (size_t)s * 32768 +
                                  (size_t)cg * 16384 + (size_t)w * 4096 + (size_t)l * 16;
      const unsigned char *ep[4], *pp[4];
#pragma unroll
      for (int j = 0; j < 4; ++j) { ep[j] = encw + j * 1024; pp[j] = prvw + j * 1024; }
      auto ISSs = [&](int t) __attribute__((always_inline)) {
        if (t < 8) {
#pragma unroll
          for (int j = 0; j < 4; ++j) { ldx4(bvr[t & 3][j], ep[j]); ep[j] += 4096; }
        } else {
#pragma unroll
          for (int j = 0; j < 4; ++j) ldx4(bvr[t & 3][j], pp[j]);
        }
      };
      ISSs(0); ISSs(1); ISSs(2); ISSs(3);
#pragma unroll
      for (int t = 0; t < 9; ++t) {
        if (t <= 5) VMW(12);
        else if (t == 6) VMW(8);
        else if (t == 7) VMW(4);
        else VMW(0);
        __builtin_amdgcn_sched_barrier(0);
#pragma unroll
        for (int i = 0; i < 4; ++i)
#pragma unroll
          for (int j = 0; j < 4; ++j)
            acc[i][j] = __builtin_amdgcn_mfma_f32_16x16x32_bf16(
                (t < 8) ? avr[i][t] : avp[i], bvr[t & 3][j], acc[i][j], 0, 0, 0);
        if (t + 4 <= 8) ISSs(t + 4);
      }

      // ---- per-wave wait: own 16 producers >= s+1; guard g2 >= s-4 ----
      waitWave((unsigned)(s + 1), (s >= 5) ? (unsigned)(s - 4) : 1u);

      // ---- recurrent half: h1[s-1] -> LDS landing (all 32 in flight) ----
      if (s > 0) {
        const unsigned char* h1b = ws + OFF_PS_H1R + (size_t)((s - 1) & 7) * 262144 +
                                   cfragW + (size_t)l * 16;
#pragma unroll
        for (int g = 0; g < 8; ++g)
#pragma unroll
          for (int j = 0; j < 4; ++j)
            __builtin_amdgcn_global_load_lds((GPTR)(h1b + g * 4096 + j * 1024),
                                             (LPTR)(landW + g * 4096 + j * 1024), 16, 0, 17);
#pragma unroll
        for (int t = 0; t < 8; ++t) {
          if (t == 0) VMW(28);
          else if (t == 1) VMW(24);
          else if (t == 2) VMW(20);
          else if (t == 3) VMW(16);
          else if (t == 4) VMW(12);
          else if (t == 5) VMW(8);
          else if (t == 6) VMW(4);
          else VMW(0);
          __builtin_amdgcn_sched_barrier(0);
          bf16x8 bv[4];
#pragma unroll
          for (int j = 0; j < 4; ++j)
            bv[j] = *(const bf16x8*)(landW + t * 4096 + j * 1024 + l * 16);
#pragma unroll
          for (int i = 0; i < 4; ++i)
#pragma unroll
            for (int j = 0; j < 4; ++j)
              acc[i][j] = __builtin_amdgcn_mfma_f32_16x16x32_bf16(avr[i][8 + t], bv[j],
                                                                  acc[i][j], 0, 0, 0);
        }
      }

      // ---- epilogue: barrier (landing fully consumed) -> red -> LSTM -> store ----
      __syncthreads();
#pragma unroll
      for (int i = 0; i < 4; ++i)
#pragma unroll
        for (int j = 0; j < 4; ++j)
#pragma unroll
          for (int q = 0; q < 4; ++q)
            red[w][16 * i + khi * 4 + q][16 * j + r15] = acc[i][j][q];
      __syncthreads();
      {
        unsigned hm[4];
#pragma unroll
        for (int u = 0; u < 4; ++u) {
          float gt[4];
#pragma unroll
          for (int g = 0; g < 4; ++g) {
            int row = 16 * g + quad * 4 + u;
            gt[g] = red[0][row][ecol] + red[1][row][ecol] + red[2][row][ecol] +
                    red[3][row][ecol] + pstb[g][u];
          }
          float ci = sigm(gt[0]), cf = sigm(gt[1]), cgt = tanh_(gt[2]), co = sigm(gt[3]);
          cst[u] = cf * cst[u] + ci * cgt;
          hm[u] = f2bf(co * tanh_(cst[u]));
        }
        unsigned long long hv = (unsigned long long)(hm[0] | (hm[1] << 16)) |
                                ((unsigned long long)(hm[2] | (hm[3] << 16)) << 32);
        const void* ha = ws + OFF_PS_H1R + (size_t)(s & 7) * 262144 + hfragOff;
        asm volatile("global_store_dwordx2 %0, %1, off sc1" ::"v"(ha), "v"(hv) : "memory");
      }
    } else if (g2run) {
      // ---- per-wave wait: g1 16 producers >= s; own 16 >= s+1 ----
      waitWave((unsigned)s, (unsigned)(s + 1));

      f32x4 acc[4][4];
      f32x4 facc[4];
#pragma unroll
      for (int i = 0; i < 4; ++i) {
        facc[i] = zero4;
#pragma unroll
        for (int j = 0; j < 4; ++j) acc[i][j] = zero4;
      }
      const unsigned char* s1 = ws + OFF_PS_H1R + (size_t)((s - 2) & 7) * 262144 +
                                cfragW + (size_t)l * 16;   // h1[s-2]
      const unsigned char* s2 = ws + OFF_H2 + (size_t)((s + 1) & 1) * 262144 +
                                cfragW + (size_t)l * 16;   // h2[s-3]
      auto ISSL2 = [&](int g) __attribute__((always_inline)) {
        const unsigned char* src = (g < 8) ? (s1 + g * 4096) : (s2 + (g - 8) * 4096);
        unsigned char* dst = landW + (g & 7) * 4096;
#pragma unroll
        for (int j = 0; j < 4; ++j)
          __builtin_amdgcn_global_load_lds((GPTR)(src + j * 1024),
                                           (LPTR)(dst + j * 1024), 16, 0, 17);
      };
#pragma unroll
      for (int g = 0; g < 8; ++g) ISSL2(g);
#pragma unroll
      for (int t = 0; t < 16; ++t) {
        if (t <= 8) VMW(28);
        else if (t == 9) VMW(24);
        else if (t == 10) VMW(20);
        else if (t == 11) VMW(16);
        else if (t == 12) VMW(12);
        else if (t == 13) VMW(8);
        else if (t == 14) VMW(4);
        else VMW(0);
        __builtin_amdgcn_sched_barrier(0);
        bf16x8 bv[4];
#pragma unroll
        for (int j = 0; j < 4; ++j)
          bv[j] = *(const bf16x8*)(landW + (t & 7) * 4096 + j * 1024 + l * 16);
        if (g2a) {
#pragma unroll
          for (int i = 0; i < 4; ++i)
#pragma unroll
            for (int j = 0; j < 4; ++j)
              acc[i][j] = __builtin_amdgcn_mfma_f32_16x16x32_bf16(avr[i][t], bv[j],
                                                                  acc[i][j], 0, 0, 0);
        }
        if (fca && t >= 8) {
#pragma unroll
          for (int j = 0; j < 4; ++j)
            facc[j] = __builtin_amdgcn_mfma_f32_16x16x32_bf16(fcav[t - 8], bv[j],
                                                              facc[j], 0, 0, 0);
        }
        if (t + 8 <= 15) ISSL2(t + 8);
      }

      // ---- epilogues: barrier -> red/fcred -> compute -> stores ----
      __syncthreads();
      if (g2a) {
#pragma unroll
        for (int i = 0; i < 4; ++i)
#pragma unroll
          for (int j = 0; j < 4; ++j)
#pragma unroll
            for (int q = 0; q < 4; ++q)
              red[w][16 * i + khi * 4 + q][16 * j + r15] = acc[i][j][q];
      }
      if (fca) {
#pragma unroll
        for (int j = 0; j < 4; ++j)
#pragma unroll
          for (int q = 0; q < 4; ++q)
            fcred[w][khi * 4 + q][16 * j + r15] = facc[j][q];
      }
      __syncthreads();
      if (g2a) {
        const float* B2 = (const float*)(ws + OFF_BIAS2);
        float pb[4][4];
#pragma unroll
        for (int g = 0; g < 4; ++g)
#pragma unroll
          for (int u = 0; u < 4; ++u)
            pb[g][u] = B2[rb * 64 + 16 * g + quad * 4 + u];
        unsigned hm[4];
#pragma unroll
        for (int u = 0; u < 4; ++u) {
          float gt[4];
#pragma unroll
          for (int g = 0; g < 4; ++g) {
            int row = 16 * g + quad * 4 + u;
            gt[g] = red[0][row][ecol] + red[1][row][ecol] + red[2][row][ecol] +
                    red[3][row][ecol] + pb[g][u];
          }
          float ci = sigm(gt[0]), cf = sigm(gt[1]), cgt = tanh_(gt[2]), co = sigm(gt[3]);
          cst[u] = cf * cst[u] + ci * cgt;
          hm[u] = f2bf(co * tanh_(cst[u]));
        }
        unsigned long long hv = (unsigned long long)(hm[0] | (hm[1] << 16)) |
                                ((unsigned long long)(hm[2] | (hm[3] << 16)) << 32);
        const void* ha = ws + OFF_H2 + (size_t)(s & 1) * 262144 + hfragOff;
        asm volatile("global_store_dwordx2 %0, %1, off sc1" ::"v"(ha), "v"(hv) : "memory");
      }
      if (fca) {
        const int t0 = s - 3;
#pragma unroll
        for (int q = 0; q < 4; ++q) {
          int m = u6 * 16 + quad * 4 + q;
          float v = fcred[0][quad * 4 + q][ecol] + fcred[1][quad * 4 + q][ecol] +
                    fcred[2][quad * 4 + q][ecol] + fcred[3][quad * 4 + q][ecol] + fcbr[q];
          if (m < 80) out[((size_t)(cg * 64 + ecol) * 80 + m) * 2000 + t0] = v;
        }
      }
    }

    // ---- publish epoch: drain block stores, then RELEASE store ----
    VMW(0);
    __syncthreads();
    if (tid == 0) epPub((unsigned)(s + 2));
  }
}

// --------------------------------- launcher ---------------------------------
extern "C" void kernel_launch(void* const* d_in, const int* in_sizes, int n_in,
                              void* d_out, int out_size, void* d_ws, size_t ws_size,
                              hipStream_t stream) {
  (void)in_sizes; (void)n_in; (void)out_size;
  const float* enc  = (const float*)d_in[0];
  const float* styl = (const float*)d_in[1];
  const float* mel  = (const float*)d_in[2];
  const float* Wih1 = (const float*)d_in[3];
  const float* Whh1 = (const float*)d_in[4];
  const float* bih1 = (const float*)d_in[5];
  const float* bhh1 = (const float*)d_in[6];
  const float* Wih2 = (const float*)d_in[7];
  const float* Whh2 = (const float*)d_in[8];
  const float* bih2 = (const float*)d_in[9];
  const float* bhh2 = (const float*)d_in[10];
  const float* fcw  = (const float*)d_in[11];
  const float* fcb  = (const float*)d_in[12];
  unsigned char* ws = (unsigned char*)d_ws;
  float* out = (float*)d_out;
  if (ws_size < WS_NEED) return;

  hipMemsetAsync(ws + OFF_PREV, 0, (size_t)(WS_NEED - OFF_PREV), stream);
  k_pack_w1<<<16384, 256, 0, stream>>>(Wih1, Whh1, ws);
  k_pack_w2<<<16384, 256, 0, stream>>>(Wih2, Whh2, ws);
  k_bias2<<<16, 256, 0, stream>>>(bih2, bhh2, ws);
  k_pack_wprev<<<2048, 256, 0, stream>>>(Wih1, ws);
  k_pack_fc<<<384, 256, 0, stream>>>(fcw, ws);
  k_styleT<<<160, 256, 0, stream>>>(styl, (float*)(ws + OFF_STYLET));
  k_pstyle<<<2048, 256, 0, stream>>>(Wih1, bih1, bhh1, (float*)(ws + OFF_STYLET), ws);
  k_pack_enc<<<51200, 256, 0, stream>>>(enc, ws);   // overwrites STYLET region (done with it)
  k_pack_prev<<<dim3(32, 128), 256, 0, stream>>>(mel, ws);
  k_persist<<<256, 256, 0, stream>>>(ws, out, fcb);
}